// Round 7
// baseline (477.834 us; speedup 1.0000x reference)
//
#include <hip/hip_runtime.h>
#include <hip/hip_bf16.h>

// GeodesicAttention: B=4, T=2048, D=1024, R=32
//   y = x @ U; p[t,j] = exp(2 y_t.y_j - n_j - n_t) in (0,1], NO online max.
// Round 13 = round 12 with geo_fused's schedule reordered (prep/reduce
// byte-identical, verified):
//   per iter: STAGE(it+1) -> prefetch aj/njv(it+1) -> scores(it) [zero-wait:
//   operands drained by PREVIOUS barrier] -> PV(it) -> __syncthreads.
//   The barrier's vmcnt(0) drain now has a full scores+PV of coverage
//   (round 12: scores stalled ~300-600cy/iter waiting its own aj loads and,
//   via in-order vmcnt retirement, the just-issued STAGE).
//   + s_setprio(1) around the PV MFMA cluster (4 blocks/CU drift out of
//   phase -> scheduler can prefer MFMA-phase waves).
#define B_ 4
#define T_ 2048
#define D_ 1024
#define R_ 32
#define XP 136   // LDS row stride in shorts (272B = 17*16B)

typedef __attribute__((ext_vector_type(8))) short short8;
typedef __attribute__((ext_vector_type(4))) float f32x4;
typedef __attribute__((ext_vector_type(4))) unsigned short us4;
typedef __attribute__((ext_vector_type(8))) unsigned short us8;

__device__ __forceinline__ unsigned short f2bf(float f) {
  union { float f; unsigned u; } v; v.f = f;
  unsigned r = (v.u + 0x7fffu + ((v.u >> 16) & 1u)) >> 16;
  return (unsigned short)r;
}
__device__ __forceinline__ float bf2f(unsigned short h) {
  union { unsigned u; float f; } v; v.u = (unsigned)h << 16;
  return v.f;
}
__device__ __forceinline__ unsigned pk2bf(float a, float b) {
  union { __hip_bfloat162 h; unsigned u; } v;
  v.h = __float22bfloat162_rn(make_float2(a, b));   // v_cvt_pk_bf16_f32 (RNE)
  return v.u;
}

// ---------------- prep: xt + Ut (in-LDS) + partial y ------------------------
// Block = 128 t x 128 d. grid (T/128, B, D/128).  (verified round 12)
__global__ __launch_bounds__(256)
void geo_prep(const float* __restrict__ x, const float* __restrict__ U,
              unsigned short* __restrict__ xt, float* __restrict__ ypart) {
  __shared__ unsigned short xs[128 * XP];   // bf16 x tile [t][d], granule-XOR
  __shared__ unsigned short uts[32 * XP];   // bf16 U^T slab [r][d]
  const int bb = blockIdx.y, t0 = blockIdx.x * 128, d0 = blockIdx.z * 128;
  const int tid = threadIdx.x, w = tid >> 6, lane = tid & 63;
  const int m = lane & 15, quad = lane >> 4;

  f32x4 uv[4];
  #pragma unroll
  for (int p = 0; p < 4; p++) {
    const int i4 = p * 256 + tid;            // (du = i4>>3, ru4 = i4&7)
    uv[p] = *(const f32x4*)(U + (size_t)(d0 + (i4 >> 3)) * R_ + (i4 & 7) * 4);
  }
  f32x4 xv[16];
  #pragma unroll
  for (int p = 0; p < 16; p++) {
    const int i4 = p * 256 + tid;            // (r = i4>>5, c4 = i4&31)
    xv[p] = *(const f32x4*)(x + ((size_t)bb * T_ + t0 + (i4 >> 5)) * D_ + d0 + (i4 & 31) * 4);
  }
  #pragma unroll
  for (int p = 0; p < 4; p++) {
    const int i4 = p * 256 + tid; const int du = i4 >> 3, ru4 = i4 & 7;
    #pragma unroll
    for (int k = 0; k < 4; k++) uts[(ru4 * 4 + k) * XP + du] = f2bf(uv[p][k]);
  }
  #pragma unroll
  for (int p = 0; p < 16; p++) {
    const int i4 = p * 256 + tid; const int r = i4 >> 5, c4 = i4 & 31;
    union { us4 c; unsigned u[2]; } cc;
    cc.u[0] = pk2bf(xv[p][0], xv[p][1]);
    cc.u[1] = pk2bf(xv[p][2], xv[p][3]);
    // granule g = c4>>1 (16B), physical granule = g ^ (r&7)
    *(us4*)&xs[r * XP + ((c4 >> 1) ^ (r & 7)) * 8 + (c4 & 1) * 4] = cc.c;
  }
  __syncthreads();
  // xt transposed store: thread = 8x8 subtile; rows t = ts*8+k -> granule dsb^k
  {
    const int ts = tid & 15, dsb = tid >> 4;
    us8 rowv[8];
    #pragma unroll
    for (int k = 0; k < 8; k++)
      rowv[k] = *(const us8*)&xs[(ts * 8 + k) * XP + ((dsb ^ k) * 8)];
    unsigned short* xo = xt + ((size_t)bb * D_ + d0 + dsb * 8) * T_ + t0 + ts * 8;
    #pragma unroll
    for (int dd = 0; dd < 8; dd++) {
      us8 o;
      #pragma unroll
      for (int k = 0; k < 8; k++) o[k] = rowv[k][dd];
      *(us8*)(xo + (size_t)dd * T_) = o;
    }
  }
  // partial y: A = x rows (t, 32/wave), B = uts rows (r), K = 128
  f32x4 acc[2][2];
  #pragma unroll
  for (int i = 0; i < 2; i++)
    #pragma unroll
    for (int j = 0; j < 2; j++) acc[i][j] = (f32x4){0.f, 0.f, 0.f, 0.f};
  #pragma unroll
  for (int ks = 0; ks < 4; ks++) {
    const int ko = ks * 32 + quad * 8;
    const int go = ((ks * 4 + quad) ^ (m & 7)) * 8;   // swizzled granule offset
    short8 a0 = *(const short8*)&xs[(w * 32 + m) * XP + go];
    short8 a1 = *(const short8*)&xs[(w * 32 + 16 + m) * XP + go];
    short8 b0 = *(const short8*)&uts[m * XP + ko];
    short8 b1 = *(const short8*)&uts[(16 + m) * XP + ko];
    acc[0][0] = __builtin_amdgcn_mfma_f32_16x16x32_bf16(a0, b0, acc[0][0], 0, 0, 0);
    acc[0][1] = __builtin_amdgcn_mfma_f32_16x16x32_bf16(a0, b1, acc[0][1], 0, 0, 0);
    acc[1][0] = __builtin_amdgcn_mfma_f32_16x16x32_bf16(a1, b0, acc[1][0], 0, 0, 0);
    acc[1][1] = __builtin_amdgcn_mfma_f32_16x16x32_bf16(a1, b1, acc[1][1], 0, 0, 0);
  }
  #pragma unroll
  for (int tb = 0; tb < 2; tb++)
    #pragma unroll
    for (int nb = 0; nb < 2; nb++)
      *(f32x4*)(ypart + ((size_t)(blockIdx.z * B_ + bb) * R_ + nb * 16 + m) * T_
                + t0 + w * 32 + tb * 16 + quad * 4) = acc[tb][nb];
}

// ---------------- reduce: y = sum_s ypart; ybf (exp2-scaled), nsq -----------
// Block = 32 t. grid (T/32, B). SCALE = sqrt(2/ln2).  (verified round 12)
__global__ __launch_bounds__(256)
void geo_reduce(const float* __restrict__ ypart, unsigned short* __restrict__ ybf,
                float* __restrict__ nsq) {
  __shared__ float ls[32][36];   // [r][t], padded
  const int t0 = blockIdx.x * 32, bb = blockIdx.y;
  const int tid = threadIdx.x;
  {
    const int r = tid >> 3, t4 = (tid & 7) * 4;
    f32x4 v = {0.f, 0.f, 0.f, 0.f};
    #pragma unroll
    for (int s = 0; s < 8; s++) {
      f32x4 p = *(const f32x4*)(ypart + ((size_t)(s * B_ + bb) * R_ + r) * T_ + t0 + t4);
      #pragma unroll
      for (int k = 0; k < 4; k++) v[k] += p[k];
    }
    *(f32x4*)&ls[r][t4] = v;
  }
  __syncthreads();
  const int t = tid >> 3, r4 = (tid & 7) * 4;
  us4 pk; float part = 0.f;
  #pragma unroll
  for (int k = 0; k < 4; k++) {
    const unsigned short h = f2bf(1.69864446f * ls[r4 + k][t]);
    const float bv = bf2f(h); part += bv * bv; pk[k] = h;
  }
  *(us4*)(ybf + ((size_t)bb * T_ + t0 + t) * R_ + r4) = pk;
  part += __shfl_xor(part, 1, 64);
  part += __shfl_xor(part, 2, 64);
  part += __shfl_xor(part, 4, 64);
  if ((tid & 7) == 0) nsq[bb * T_ + t0 + t] = 0.5f * part;
}

// ---------------- fused: out[t, d-slab] = (exp2-P @ xt^T) / rowsum ----------
// Block = (t-tile 64) x (d-slab 128); wave w owns out rows [w*16, w*16+16).
// grid 1024 = 4 blocks/CU. P stays in registers (permuted-fragment scores).
__global__ __launch_bounds__(256, 4)
void geo_fused(const unsigned short* __restrict__ ybf,
               const float* __restrict__ nsq,
               const unsigned short* __restrict__ xt,
               float* __restrict__ out) {
  __shared__ unsigned short Bs[2][128 * 64];   // xt tiles, XOR-swizzled (32 KB)
  __shared__ float l_s[64];
  const int bz = blockIdx.z, id = blockIdx.x;
  const int d0 = (id & 7) * 128;   // id%8 -> d-slab: each XCD reuses one xt panel
  const int t0 = (id >> 3) * 64;
  const int tid = threadIdx.x, w = tid >> 6, lane = tid & 63;
  const int m = lane & 15, quad = lane >> 4;
  const int srow = lane >> 3, sslot = lane & 7;
  const int tw = w * 16;

  const unsigned short* yb = ybf + (size_t)bz * T_ * R_;
  const float* nq = nsq + bz * T_;
  const unsigned short* Xb = xt + ((size_t)bz * D_ + d0) * T_;

// stage 128 d-rows x 64 j into Bs[BUF]; 4 instrs/wave, linear LDS dest,
// pre-swizzled global source.
#define STAGE(J0, BUF) do {                                                      \
    _Pragma("unroll")                                                            \
    for (int cc = 0; cc < 4; cc++) {                                             \
      const int rbase = w * 32 + cc * 8;                                         \
      const int row = rbase + srow;                                              \
      const int sw = (sslot ^ (row & 7)) * 8;                                    \
      __builtin_amdgcn_global_load_lds(                                          \
        (const __attribute__((address_space(1))) void*)(Xb + (size_t)row * T_ + (J0) + sw), \
        (__attribute__((address_space(3))) void*)(&Bs[BUF][rbase * 64]), 16, 0, 0); \
    } } while (0)

// one 64-j iteration. Entry invariant: Bs[BUF] staged & barrier'd; AJC/NJC
// (tile IT) complete in regs (drained by the previous barrier).
#define BODY(IT, AJC, NJC, AJN, NJN, BUF) do {                                   \
    if ((IT) + 1 < 32) STAGE(((IT) + 1) * 64, (BUF) ^ 1);                        \
    {                                                                            \
      const int jn0 = (((IT) + 1) & 31) * 64;                                    \
      _Pragma("unroll")                                                          \
      for (int ja = 0; ja < 4; ja++) {                                           \
        const int jr = 32 * (ja >> 1) + 8 * (m >> 2) + (ja & 1) * 4 + (m & 3);   \
        AJN[ja] = *(const short8*)(yb + (size_t)(jn0 + jr) * R_ + quad * 8);     \
        NJN[ja] = *(const f32x4*)(nq + jn0 + 32 * (ja >> 1) + (ja & 1) * 4 + 8 * quad); \
      }                                                                          \
    }                                                                            \
    {                                                                            \
      union { short8 s; unsigned u[4]; } pf[2];                                  \
      _Pragma("unroll")                                                          \
      for (int ja = 0; ja < 4; ja++) {                                           \
        f32x4 cin;                                                               \
        _Pragma("unroll")                                                        \
        for (int r = 0; r < 4; r++) cin[r] = nnt - NJC[ja][r];                   \
        f32x4 c = __builtin_amdgcn_mfma_f32_16x16x32_bf16(AJC[ja], at, cin, 0, 0, 0); \
        f32x4 p;                                                                 \
        _Pragma("unroll")                                                        \
        for (int r = 0; r < 4; r++) {                                            \
          p[r] = __builtin_amdgcn_exp2f(c[r]);                                   \
          lsum4[r] += p[r];                                                      \
        }                                                                        \
        pf[ja >> 1].u[(ja & 1) * 2 + 0] = pk2bf(p[0], p[1]);                     \
        pf[ja >> 1].u[(ja & 1) * 2 + 1] = pk2bf(p[2], p[3]);                     \
      }                                                                          \
      __builtin_amdgcn_s_setprio(1);                                             \
      _Pragma("unroll")                                                          \
      for (int kb = 0; kb < 2; kb++) {                                           \
        short8 bfr[8];                                                           \
        _Pragma("unroll")                                                        \
        for (int nb = 0; nb < 8; nb++)                                           \
          bfr[nb] = *(const short8*)&Bs[BUF][(nb * 16 + m) * 64 + (((kb * 4 + quad) ^ (m & 7)) * 8)]; \
        _Pragma("unroll")                                                        \
        for (int nb = 0; nb < 8; nb++)                                           \
          acc[nb] = __builtin_amdgcn_mfma_f32_16x16x32_bf16(pf[kb].s, bfr[nb], acc[nb], 0, 0, 0); \
      }                                                                          \
      __builtin_amdgcn_s_setprio(0);                                             \
    }                                                                            \
    __syncthreads();                                                             \
  } while (0)

  // hoisted t-side fragment (16 rows per wave)
  short8 at = *(const short8*)(yb + (size_t)(t0 + tw + m) * R_ + quad * 8);
  const float nnt = -nq[t0 + tw + m];
  f32x4 lsum4 = {0.f, 0.f, 0.f, 0.f};

  f32x4 acc[8];
  #pragma unroll
  for (int j = 0; j < 8; j++) acc[j] = (f32x4){0.f, 0.f, 0.f, 0.f};

  // prologue: stage tile 0 + prefetch tile-0 fragments, then barrier
  short8 ajA[4], ajB[4]; f32x4 njA[4], njB[4];
  STAGE(0, 0);
  #pragma unroll
  for (int ja = 0; ja < 4; ja++) {
    const int jr = 32 * (ja >> 1) + 8 * (m >> 2) + (ja & 1) * 4 + (m & 3);
    ajA[ja] = *(const short8*)(yb + (size_t)jr * R_ + quad * 8);
    njA[ja] = *(const f32x4*)(nq + 32 * (ja >> 1) + (ja & 1) * 4 + 8 * quad);
  }
  __syncthreads();

  for (int it2 = 0; it2 < 16; it2++) {
    BODY(2 * it2,     ajA, njA, ajB, njB, 0);
    BODY(2 * it2 + 1, ajB, njB, ajA, njA, 1);
  }

  // row sums: butterfly over quads, publish via tiny LDS
  float lsum = lsum4[0] + lsum4[1] + lsum4[2] + lsum4[3];
  lsum += __shfl_xor(lsum, 16, 64);
  lsum += __shfl_xor(lsum, 32, 64);
  if (quad == 0) l_s[tw + m] = lsum;
  __syncthreads();
  // epilogue: out = acc / l   (C rows = quad*4+r, cols = m)
  {
    f32x4 lv = *(const f32x4*)&l_s[tw + quad * 4];
    f32x4 inv;
    #pragma unroll
    for (int r = 0; r < 4; r++) inv[r] = 1.f / lv[r];
    float* ob = out + ((size_t)bz * T_ + t0 + tw + quad * 4) * D_ + d0;
    #pragma unroll
    for (int nb = 0; nb < 8; nb++)
      #pragma unroll
      for (int r = 0; r < 4; r++)
        ob[(size_t)r * D_ + nb * 16 + m] = acc[nb][r] * inv[r];
  }
#undef BODY
#undef STAGE
}

extern "C" void kernel_launch(void* const* d_in, const int* in_sizes, int n_in,
                              void* d_out, int out_size, void* d_ws, size_t ws_size,
                              hipStream_t stream) {
  const float* x = (const float*)d_in[0];
  const float* U = (const float*)d_in[1];
  float* out = (float*)d_out;

  const size_t xt_b  = (size_t)B_ * D_ * T_ * 2;      // 16 MB
  const size_t ybf_b = (size_t)B_ * T_ * R_ * 2;      // 512 KB
  const size_t nsq_b = (size_t)B_ * T_ * 4;           // 32 KB
  const size_t yp_b  = (size_t)8 * B_ * R_ * T_ * 4;  // 8 MB partial y [slab][b][r][t]

  char* wp = (char*)d_ws;
  unsigned short* xtp = (unsigned short*)wp;                 wp += xt_b;
  unsigned short* ybf = (unsigned short*)wp;                 wp += ybf_b;
  float* nsq = (float*)wp;                                   wp += nsq_b;
  float* ypart = (float*)wp;                                 wp += yp_b;
  (void)ws_size; (void)in_sizes; (void)n_in; (void)out_size;

  hipLaunchKernelGGL(geo_prep, dim3(T_ / 128, B_, D_ / 128), dim3(256), 0, stream,
                     x, U, xtp, ypart);
  hipLaunchKernelGGL(geo_reduce, dim3(T_ / 32, B_), dim3(256), 0, stream,
                     ypart, ybf, nsq);
  hipLaunchKernelGGL(geo_fused, dim3((T_ / 64) * (D_ / 128), 1, B_), dim3(256), 0, stream,
                     ybf, nsq, xtp, out);
}

// Round 8
// 168.896 us; speedup vs baseline: 2.8292x; 2.8292x over previous
//
#include <hip/hip_runtime.h>
#include <hip/hip_bf16.h>

// GeodesicAttention: B=4, T=2048, D=1024, R=32
//   y = x @ U; p[t,j] = exp(2 y_t.y_j - n_j - n_t) in (0,1], NO online max.
// Round 14 = round 13 (verified 80.5us fused) with waves split over d:
//   wave (th=w&1, dh=w>>1) owns 32t x 64d of output. Each wave reads only
//   64 of 128 Bs rows -> PV LDS-read traffic HALVES (the round-13 counters'
//   dominant wall: 4 waves x 16KB/iter = 2.1GB = ~41us at 85B/cyc/CU).
//   Scores computed redundantly per d-half (+VALU on the parallel pipe).
//   Schedule is round-13's EXACT verified order (aj -> scores -> barrier ->
//   STAGE(it+1) -> PV); round-7-style cross-body register prefetch is
//   forbidden (live-range > (256,4)'s 128-VGPR cap -> scratch spill
//   catastrophe: 1.08GB scratch writes measured).
//   prep/reduce byte-identical (verified round 12).
#define B_ 4
#define T_ 2048
#define D_ 1024
#define R_ 32
#define XP 136   // LDS row stride in shorts (272B = 17*16B)

typedef __attribute__((ext_vector_type(8))) short short8;
typedef __attribute__((ext_vector_type(4))) float f32x4;
typedef __attribute__((ext_vector_type(4))) unsigned short us4;
typedef __attribute__((ext_vector_type(8))) unsigned short us8;

__device__ __forceinline__ unsigned short f2bf(float f) {
  union { float f; unsigned u; } v; v.f = f;
  unsigned r = (v.u + 0x7fffu + ((v.u >> 16) & 1u)) >> 16;
  return (unsigned short)r;
}
__device__ __forceinline__ float bf2f(unsigned short h) {
  union { unsigned u; float f; } v; v.u = (unsigned)h << 16;
  return v.f;
}
__device__ __forceinline__ unsigned pk2bf(float a, float b) {
  union { __hip_bfloat162 h; unsigned u; } v;
  v.h = __float22bfloat162_rn(make_float2(a, b));   // v_cvt_pk_bf16_f32 (RNE)
  return v.u;
}

// ---------------- prep: xt + Ut (in-LDS) + partial y ------------------------
// Block = 128 t x 128 d. grid (T/128, B, D/128).  (verified round 12)
__global__ __launch_bounds__(256)
void geo_prep(const float* __restrict__ x, const float* __restrict__ U,
              unsigned short* __restrict__ xt, float* __restrict__ ypart) {
  __shared__ unsigned short xs[128 * XP];   // bf16 x tile [t][d], granule-XOR
  __shared__ unsigned short uts[32 * XP];   // bf16 U^T slab [r][d]
  const int bb = blockIdx.y, t0 = blockIdx.x * 128, d0 = blockIdx.z * 128;
  const int tid = threadIdx.x, w = tid >> 6, lane = tid & 63;
  const int m = lane & 15, quad = lane >> 4;

  f32x4 uv[4];
  #pragma unroll
  for (int p = 0; p < 4; p++) {
    const int i4 = p * 256 + tid;            // (du = i4>>3, ru4 = i4&7)
    uv[p] = *(const f32x4*)(U + (size_t)(d0 + (i4 >> 3)) * R_ + (i4 & 7) * 4);
  }
  f32x4 xv[16];
  #pragma unroll
  for (int p = 0; p < 16; p++) {
    const int i4 = p * 256 + tid;            // (r = i4>>5, c4 = i4&31)
    xv[p] = *(const f32x4*)(x + ((size_t)bb * T_ + t0 + (i4 >> 5)) * D_ + d0 + (i4 & 31) * 4);
  }
  #pragma unroll
  for (int p = 0; p < 4; p++) {
    const int i4 = p * 256 + tid; const int du = i4 >> 3, ru4 = i4 & 7;
    #pragma unroll
    for (int k = 0; k < 4; k++) uts[(ru4 * 4 + k) * XP + du] = f2bf(uv[p][k]);
  }
  #pragma unroll
  for (int p = 0; p < 16; p++) {
    const int i4 = p * 256 + tid; const int r = i4 >> 5, c4 = i4 & 31;
    union { us4 c; unsigned u[2]; } cc;
    cc.u[0] = pk2bf(xv[p][0], xv[p][1]);
    cc.u[1] = pk2bf(xv[p][2], xv[p][3]);
    // granule g = c4>>1 (16B), physical granule = g ^ (r&7)
    *(us4*)&xs[r * XP + ((c4 >> 1) ^ (r & 7)) * 8 + (c4 & 1) * 4] = cc.c;
  }
  __syncthreads();
  // xt transposed store: thread = 8x8 subtile; rows t = ts*8+k -> granule dsb^k
  {
    const int ts = tid & 15, dsb = tid >> 4;
    us8 rowv[8];
    #pragma unroll
    for (int k = 0; k < 8; k++)
      rowv[k] = *(const us8*)&xs[(ts * 8 + k) * XP + ((dsb ^ k) * 8)];
    unsigned short* xo = xt + ((size_t)bb * D_ + d0 + dsb * 8) * T_ + t0 + ts * 8;
    #pragma unroll
    for (int dd = 0; dd < 8; dd++) {
      us8 o;
      #pragma unroll
      for (int k = 0; k < 8; k++) o[k] = rowv[k][dd];
      *(us8*)(xo + (size_t)dd * T_) = o;
    }
  }
  // partial y: A = x rows (t, 32/wave), B = uts rows (r), K = 128
  f32x4 acc[2][2];
  #pragma unroll
  for (int i = 0; i < 2; i++)
    #pragma unroll
    for (int j = 0; j < 2; j++) acc[i][j] = (f32x4){0.f, 0.f, 0.f, 0.f};
  #pragma unroll
  for (int ks = 0; ks < 4; ks++) {
    const int ko = ks * 32 + quad * 8;
    const int go = ((ks * 4 + quad) ^ (m & 7)) * 8;   // swizzled granule offset
    short8 a0 = *(const short8*)&xs[(w * 32 + m) * XP + go];
    short8 a1 = *(const short8*)&xs[(w * 32 + 16 + m) * XP + go];
    short8 b0 = *(const short8*)&uts[m * XP + ko];
    short8 b1 = *(const short8*)&uts[(16 + m) * XP + ko];
    acc[0][0] = __builtin_amdgcn_mfma_f32_16x16x32_bf16(a0, b0, acc[0][0], 0, 0, 0);
    acc[0][1] = __builtin_amdgcn_mfma_f32_16x16x32_bf16(a0, b1, acc[0][1], 0, 0, 0);
    acc[1][0] = __builtin_amdgcn_mfma_f32_16x16x32_bf16(a1, b0, acc[1][0], 0, 0, 0);
    acc[1][1] = __builtin_amdgcn_mfma_f32_16x16x32_bf16(a1, b1, acc[1][1], 0, 0, 0);
  }
  #pragma unroll
  for (int tb = 0; tb < 2; tb++)
    #pragma unroll
    for (int nb = 0; nb < 2; nb++)
      *(f32x4*)(ypart + ((size_t)(blockIdx.z * B_ + bb) * R_ + nb * 16 + m) * T_
                + t0 + w * 32 + tb * 16 + quad * 4) = acc[tb][nb];
}

// ---------------- reduce: y = sum_s ypart; ybf (exp2-scaled), nsq -----------
// Block = 32 t. grid (T/32, B). SCALE = sqrt(2/ln2).  (verified round 12)
__global__ __launch_bounds__(256)
void geo_reduce(const float* __restrict__ ypart, unsigned short* __restrict__ ybf,
                float* __restrict__ nsq) {
  __shared__ float ls[32][36];   // [r][t], padded
  const int t0 = blockIdx.x * 32, bb = blockIdx.y;
  const int tid = threadIdx.x;
  {
    const int r = tid >> 3, t4 = (tid & 7) * 4;
    f32x4 v = {0.f, 0.f, 0.f, 0.f};
    #pragma unroll
    for (int s = 0; s < 8; s++) {
      f32x4 p = *(const f32x4*)(ypart + ((size_t)(s * B_ + bb) * R_ + r) * T_ + t0 + t4);
      #pragma unroll
      for (int k = 0; k < 4; k++) v[k] += p[k];
    }
    *(f32x4*)&ls[r][t4] = v;
  }
  __syncthreads();
  const int t = tid >> 3, r4 = (tid & 7) * 4;
  us4 pk; float part = 0.f;
  #pragma unroll
  for (int k = 0; k < 4; k++) {
    const unsigned short h = f2bf(1.69864446f * ls[r4 + k][t]);
    const float bv = bf2f(h); part += bv * bv; pk[k] = h;
  }
  *(us4*)(ybf + ((size_t)bb * T_ + t0 + t) * R_ + r4) = pk;
  part += __shfl_xor(part, 1, 64);
  part += __shfl_xor(part, 2, 64);
  part += __shfl_xor(part, 4, 64);
  if ((tid & 7) == 0) nsq[bb * T_ + t0 + t] = 0.5f * part;
}

// ---------------- fused: out[t, d-slab] = (exp2-P @ xt^T) / rowsum ----------
// Block = (t-tile 64) x (d-slab 128); wave (th=w&1, dh=w>>1) owns 32t x 64d.
// grid 1024 = 4 blocks/CU. P in registers (permuted-fragment scores, computed
// per d-half redundantly); each wave reads only its 64 Bs rows.
__global__ __launch_bounds__(256, 4)
void geo_fused(const unsigned short* __restrict__ ybf,
               const float* __restrict__ nsq,
               const unsigned short* __restrict__ xt,
               float* __restrict__ out) {
  __shared__ unsigned short Bs[2][128 * 64];   // xt tiles, XOR-swizzled (32 KB)
  __shared__ float l_s[64];
  const int bz = blockIdx.z, id = blockIdx.x;
  const int d0 = (id & 7) * 128;   // id%8 -> d-slab: each XCD reuses one xt panel
  const int t0 = (id >> 3) * 64;
  const int tid = threadIdx.x, w = tid >> 6, lane = tid & 63;
  const int m = lane & 15, quad = lane >> 4;
  const int srow = lane >> 3, sslot = lane & 7;
  const int th = w & 1, dh = w >> 1;

  const unsigned short* yb = ybf + (size_t)bz * T_ * R_;
  const float* nq = nsq + bz * T_;
  const unsigned short* Xb = xt + ((size_t)bz * D_ + d0) * T_;

// stage 128 d-rows x 64 j into Bs[BUF]; 4 instrs/wave, linear LDS dest,
// pre-swizzled global source. (verified round 12/13)
#define STAGE(J0, BUF) do {                                                      \
    _Pragma("unroll")                                                            \
    for (int cc = 0; cc < 4; cc++) {                                             \
      const int rbase = w * 32 + cc * 8;                                         \
      const int row = rbase + srow;                                              \
      const int sw = (sslot ^ (row & 7)) * 8;                                    \
      __builtin_amdgcn_global_load_lds(                                          \
        (const __attribute__((address_space(1))) void*)(Xb + (size_t)row * T_ + (J0) + sw), \
        (__attribute__((address_space(3))) void*)(&Bs[BUF][rbase * 64]), 16, 0, 0); \
    } } while (0)

  // hoisted t-side fragments: 2 t-strips of 16 rows each (32 t per wave)
  short8 at[2]; float nnt[2]; f32x4 lsum4[2];
  #pragma unroll
  for (int tb = 0; tb < 2; tb++) {
    at[tb] = *(const short8*)(yb + (size_t)(t0 + th * 32 + tb * 16 + m) * R_ + quad * 8);
    nnt[tb] = -nq[t0 + th * 32 + tb * 16 + m];
    lsum4[tb] = (f32x4){0.f, 0.f, 0.f, 0.f};
  }

  f32x4 acc[2][4];
  #pragma unroll
  for (int i = 0; i < 2; i++)
    #pragma unroll
    for (int j = 0; j < 4; j++) acc[i][j] = (f32x4){0.f, 0.f, 0.f, 0.f};

  STAGE(0, 0);   // prologue: tile 0 -> Bs[0]

  for (int it = 0; it < 32; ++it) {
    const int j0 = it * 64, buf = it & 1;
    // j-side fragments, PERMUTED rows: frag-row i <- global j = g(ja,i)
    short8 aj[4]; f32x4 njv[4];
    #pragma unroll
    for (int ja = 0; ja < 4; ja++) {
      const int jr = 32 * (ja >> 1) + 8 * (m >> 2) + (ja & 1) * 4 + (m & 3);
      aj[ja] = *(const short8*)(yb + (size_t)(j0 + jr) * R_ + quad * 8);
      njv[ja] = *(const f32x4*)(nq + j0 + 32 * (ja >> 1) + (ja & 1) * 4 + 8 * quad);
    }
    // scores -> exp2 -> bf16 PV A-frags, fully in registers (2 t-strips)
    union { short8 s; unsigned u[4]; } pf[2][2];
    #pragma unroll
    for (int tb = 0; tb < 2; tb++) {
      #pragma unroll
      for (int ja = 0; ja < 4; ja++) {
        f32x4 cin;
        #pragma unroll
        for (int r = 0; r < 4; r++) cin[r] = nnt[tb] - njv[ja][r];
        f32x4 c = __builtin_amdgcn_mfma_f32_16x16x32_bf16(aj[ja], at[tb], cin, 0, 0, 0);
        f32x4 p;
        #pragma unroll
        for (int r = 0; r < 4; r++) {
          p[r] = __builtin_amdgcn_exp2f(c[r]);
          lsum4[tb][r] += p[r];
        }
        pf[tb][ja >> 1].u[(ja & 1) * 2 + 0] = pk2bf(p[0], p[1]);
        pf[tb][ja >> 1].u[(ja & 1) * 2 + 1] = pk2bf(p[2], p[3]);
      }
    }
    __syncthreads();                 // drains STAGE(it); coverage = PV(it-1)+scores(it)
    if (it + 1 < 32) STAGE(j0 + 64, buf ^ 1);
    // PV on Bs[buf]: this wave reads only rows [dh*64, dh*64+64)
    #pragma unroll
    for (int kb = 0; kb < 2; kb++) {
      short8 bfr[4];
      #pragma unroll
      for (int nb = 0; nb < 4; nb++)
        bfr[nb] = *(const short8*)&Bs[buf][(dh * 64 + nb * 16 + m) * 64 + (((kb * 4 + quad) ^ (m & 7)) * 8)];
      #pragma unroll
      for (int tb = 0; tb < 2; tb++)
        #pragma unroll
        for (int nb = 0; nb < 4; nb++)
          acc[tb][nb] = __builtin_amdgcn_mfma_f32_16x16x32_bf16(pf[tb][kb].s, bfr[nb], acc[tb][nb], 0, 0, 0);
    }
  }
  // row sums: butterfly over quads; publish once (dh==0 waves; both d-halves
  // compute bit-identical sums)
  #pragma unroll
  for (int tb = 0; tb < 2; tb++) {
    float lsum = lsum4[tb][0] + lsum4[tb][1] + lsum4[tb][2] + lsum4[tb][3];
    lsum += __shfl_xor(lsum, 16, 64);
    lsum += __shfl_xor(lsum, 32, 64);
    if (quad == 0 && dh == 0) l_s[th * 32 + tb * 16 + m] = lsum;
  }
  __syncthreads();
  // epilogue: out = acc / l   (C rows = quad*4+r, cols = m)
  #pragma unroll
  for (int tb = 0; tb < 2; tb++) {
    f32x4 lv = *(const f32x4*)&l_s[th * 32 + tb * 16 + quad * 4];
    f32x4 inv;
    #pragma unroll
    for (int r = 0; r < 4; r++) inv[r] = 1.f / lv[r];
    float* ob = out + ((size_t)bz * T_ + t0 + th * 32 + tb * 16 + quad * 4) * D_ + d0 + dh * 64;
    #pragma unroll
    for (int nb = 0; nb < 4; nb++)
      #pragma unroll
      for (int r = 0; r < 4; r++)
        ob[(size_t)r * D_ + nb * 16 + m] = acc[tb][nb][r] * inv[r];
  }
#undef STAGE
}

extern "C" void kernel_launch(void* const* d_in, const int* in_sizes, int n_in,
                              void* d_out, int out_size, void* d_ws, size_t ws_size,
                              hipStream_t stream) {
  const float* x = (const float*)d_in[0];
  const float* U = (const float*)d_in[1];
  float* out = (float*)d_out;

  const size_t xt_b  = (size_t)B_ * D_ * T_ * 2;      // 16 MB
  const size_t ybf_b = (size_t)B_ * T_ * R_ * 2;      // 512 KB
  const size_t nsq_b = (size_t)B_ * T_ * 4;           // 32 KB
  const size_t yp_b  = (size_t)8 * B_ * R_ * T_ * 4;  // 8 MB partial y [slab][b][r][t]

  char* wp = (char*)d_ws;
  unsigned short* xtp = (unsigned short*)wp;                 wp += xt_b;
  unsigned short* ybf = (unsigned short*)wp;                 wp += ybf_b;
  float* nsq = (float*)wp;                                   wp += nsq_b;
  float* ypart = (float*)wp;                                 wp += yp_b;
  (void)ws_size; (void)in_sizes; (void)n_in; (void)out_size;

  hipLaunchKernelGGL(geo_prep, dim3(T_ / 128, B_, D_ / 128), dim3(256), 0, stream,
                     x, U, xtp, ypart);
  hipLaunchKernelGGL(geo_reduce, dim3(T_ / 32, B_), dim3(256), 0, stream,
                     ypart, ybf, nsq);
  hipLaunchKernelGGL(geo_fused, dim3((T_ / 64) * (D_ / 128), 1, B_), dim3(256), 0, stream,
                     ybf, nsq, xtp, out);
}

// Round 9
// 149.082 us; speedup vs baseline: 3.2052x; 1.1329x over previous
//
#include <hip/hip_runtime.h>
#include <hip/hip_bf16.h>

// GeodesicAttention: B=4, T=2048, D=1024, R=32
//   y = x @ U; p[t,j] = exp(2 y_t.y_j - n_j - n_t) in (0,1], NO online max.
// Round 15 = the round-1 VERIFIED fused (69.3us: t-tile 128, P->swizzled As
// LDS tile, quadrant PV — the best measured structure; LDS reads 0.6GB vs
// 2.1GB for all register-P variants) with its one measured defect fixed:
//   - As row stride 128B -> 136B (As[128*68]): the As write had 16 rows at
//     128B stride = same banks = 16-way conflict (2.1M conflict cycles).
//     136B shifts banks 2/row -> <=2-way (free). Same XOR granule swizzle.
//   - pk2bf (v_cvt_pk_bf16_f32) packing in the As write (verified round 6).
//   - prep/reduce byte-identical to round 8 (verified).
#define B_ 4
#define T_ 2048
#define D_ 1024
#define R_ 32
#define XP 136   // prep LDS row stride in shorts (272B = 17*16B)
#define ASTR 136 // fused As row stride in BYTES (68 shorts)

typedef __attribute__((ext_vector_type(8))) short short8;
typedef __attribute__((ext_vector_type(4))) float f32x4;
typedef __attribute__((ext_vector_type(4))) unsigned short us4;
typedef __attribute__((ext_vector_type(8))) unsigned short us8;

__device__ __forceinline__ unsigned short f2bf(float f) {
  union { float f; unsigned u; } v; v.f = f;
  unsigned r = (v.u + 0x7fffu + ((v.u >> 16) & 1u)) >> 16;
  return (unsigned short)r;
}
__device__ __forceinline__ float bf2f(unsigned short h) {
  union { unsigned u; float f; } v; v.u = (unsigned)h << 16;
  return v.f;
}
__device__ __forceinline__ unsigned pk2bf(float a, float b) {
  union { __hip_bfloat162 h; unsigned u; } v;
  v.h = __float22bfloat162_rn(make_float2(a, b));   // v_cvt_pk_bf16_f32 (RNE)
  return v.u;
}

// ---------------- prep: xt + Ut (in-LDS) + partial y ------------------------
// Block = 128 t x 128 d. grid (T/128, B, D/128).  (verified round 12)
__global__ __launch_bounds__(256)
void geo_prep(const float* __restrict__ x, const float* __restrict__ U,
              unsigned short* __restrict__ xt, float* __restrict__ ypart) {
  __shared__ unsigned short xs[128 * XP];   // bf16 x tile [t][d], granule-XOR
  __shared__ unsigned short uts[32 * XP];   // bf16 U^T slab [r][d]
  const int bb = blockIdx.y, t0 = blockIdx.x * 128, d0 = blockIdx.z * 128;
  const int tid = threadIdx.x, w = tid >> 6, lane = tid & 63;
  const int m = lane & 15, quad = lane >> 4;

  f32x4 uv[4];
  #pragma unroll
  for (int p = 0; p < 4; p++) {
    const int i4 = p * 256 + tid;            // (du = i4>>3, ru4 = i4&7)
    uv[p] = *(const f32x4*)(U + (size_t)(d0 + (i4 >> 3)) * R_ + (i4 & 7) * 4);
  }
  f32x4 xv[16];
  #pragma unroll
  for (int p = 0; p < 16; p++) {
    const int i4 = p * 256 + tid;            // (r = i4>>5, c4 = i4&31)
    xv[p] = *(const f32x4*)(x + ((size_t)bb * T_ + t0 + (i4 >> 5)) * D_ + d0 + (i4 & 31) * 4);
  }
  #pragma unroll
  for (int p = 0; p < 4; p++) {
    const int i4 = p * 256 + tid; const int du = i4 >> 3, ru4 = i4 & 7;
    #pragma unroll
    for (int k = 0; k < 4; k++) uts[(ru4 * 4 + k) * XP + du] = f2bf(uv[p][k]);
  }
  #pragma unroll
  for (int p = 0; p < 16; p++) {
    const int i4 = p * 256 + tid; const int r = i4 >> 5, c4 = i4 & 31;
    union { us4 c; unsigned u[2]; } cc;
    cc.u[0] = pk2bf(xv[p][0], xv[p][1]);
    cc.u[1] = pk2bf(xv[p][2], xv[p][3]);
    // granule g = c4>>1 (16B), physical granule = g ^ (r&7)
    *(us4*)&xs[r * XP + ((c4 >> 1) ^ (r & 7)) * 8 + (c4 & 1) * 4] = cc.c;
  }
  __syncthreads();
  // xt transposed store: thread = 8x8 subtile; rows t = ts*8+k -> granule dsb^k
  {
    const int ts = tid & 15, dsb = tid >> 4;
    us8 rowv[8];
    #pragma unroll
    for (int k = 0; k < 8; k++)
      rowv[k] = *(const us8*)&xs[(ts * 8 + k) * XP + ((dsb ^ k) * 8)];
    unsigned short* xo = xt + ((size_t)bb * D_ + d0 + dsb * 8) * T_ + t0 + ts * 8;
    #pragma unroll
    for (int dd = 0; dd < 8; dd++) {
      us8 o;
      #pragma unroll
      for (int k = 0; k < 8; k++) o[k] = rowv[k][dd];
      *(us8*)(xo + (size_t)dd * T_) = o;
    }
  }
  // partial y: A = x rows (t, 32/wave), B = uts rows (r), K = 128
  f32x4 acc[2][2];
  #pragma unroll
  for (int i = 0; i < 2; i++)
    #pragma unroll
    for (int j = 0; j < 2; j++) acc[i][j] = (f32x4){0.f, 0.f, 0.f, 0.f};
  #pragma unroll
  for (int ks = 0; ks < 4; ks++) {
    const int ko = ks * 32 + quad * 8;
    const int go = ((ks * 4 + quad) ^ (m & 7)) * 8;   // swizzled granule offset
    short8 a0 = *(const short8*)&xs[(w * 32 + m) * XP + go];
    short8 a1 = *(const short8*)&xs[(w * 32 + 16 + m) * XP + go];
    short8 b0 = *(const short8*)&uts[m * XP + ko];
    short8 b1 = *(const short8*)&uts[(16 + m) * XP + ko];
    acc[0][0] = __builtin_amdgcn_mfma_f32_16x16x32_bf16(a0, b0, acc[0][0], 0, 0, 0);
    acc[0][1] = __builtin_amdgcn_mfma_f32_16x16x32_bf16(a0, b1, acc[0][1], 0, 0, 0);
    acc[1][0] = __builtin_amdgcn_mfma_f32_16x16x32_bf16(a1, b0, acc[1][0], 0, 0, 0);
    acc[1][1] = __builtin_amdgcn_mfma_f32_16x16x32_bf16(a1, b1, acc[1][1], 0, 0, 0);
  }
  #pragma unroll
  for (int tb = 0; tb < 2; tb++)
    #pragma unroll
    for (int nb = 0; nb < 2; nb++)
      *(f32x4*)(ypart + ((size_t)(blockIdx.z * B_ + bb) * R_ + nb * 16 + m) * T_
                + t0 + w * 32 + tb * 16 + quad * 4) = acc[tb][nb];
}

// ---------------- reduce: y = sum_s ypart; ybf (exp2-scaled), nsq -----------
// Block = 32 t. grid (T/32, B). SCALE = sqrt(2/ln2).  (verified round 12)
__global__ __launch_bounds__(256)
void geo_reduce(const float* __restrict__ ypart, unsigned short* __restrict__ ybf,
                float* __restrict__ nsq) {
  __shared__ float ls[32][36];   // [r][t], padded
  const int t0 = blockIdx.x * 32, bb = blockIdx.y;
  const int tid = threadIdx.x;
  {
    const int r = tid >> 3, t4 = (tid & 7) * 4;
    f32x4 v = {0.f, 0.f, 0.f, 0.f};
    #pragma unroll
    for (int s = 0; s < 8; s++) {
      f32x4 p = *(const f32x4*)(ypart + ((size_t)(s * B_ + bb) * R_ + r) * T_ + t0 + t4);
      #pragma unroll
      for (int k = 0; k < 4; k++) v[k] += p[k];
    }
    *(f32x4*)&ls[r][t4] = v;
  }
  __syncthreads();
  const int t = tid >> 3, r4 = (tid & 7) * 4;
  us4 pk; float part = 0.f;
  #pragma unroll
  for (int k = 0; k < 4; k++) {
    const unsigned short h = f2bf(1.69864446f * ls[r4 + k][t]);
    const float bv = bf2f(h); part += bv * bv; pk[k] = h;
  }
  *(us4*)(ybf + ((size_t)bb * T_ + t0 + t) * R_ + r4) = pk;
  part += __shfl_xor(part, 1, 64);
  part += __shfl_xor(part, 2, 64);
  part += __shfl_xor(part, 4, 64);
  if ((tid & 7) == 0) nsq[bb * T_ + t0 + t] = 0.5f * part;
}

// ---------------- fused: out[t, d-slab] = (exp2-P @ xt^T) / rowsum ----------
// Block = (t-tile 128) x (d-slab 128). Wave w: scores strip t [w*32, w*32+32),
// PV quadrant wr=(w&1)*64, wc=(w>>1)*64. Loop j in 64-tiles (32 iters).
// As = P tile in LDS, 136B row stride (conflict-free writes), XOR swizzle.
__global__ __launch_bounds__(256, 2)
void geo_fused(const unsigned short* __restrict__ ybf,
               const float* __restrict__ nsq,
               const unsigned short* __restrict__ xt,
               float* __restrict__ out) {
  __shared__ unsigned short As[128 * (ASTR / 2)];  // P tile (17.4 KB, padded)
  __shared__ unsigned short Bs[128 * 64];          // xt tile (16 KB)
  __shared__ float l_s[128];
  const int bz = blockIdx.z, id = blockIdx.x;
  const int d0 = (id & 7) * 128;   // id%8 -> d-slab: each XCD reuses one xt panel
  const int t0 = (id >> 3) * 128;
  const int tid = threadIdx.x, w = tid >> 6, lane = tid & 63;
  const int m = lane & 15, quad = lane >> 4;
  const int wr = (w & 1) * 64, wc = (w >> 1) * 64;
  const int srow = lane >> 3, sslot = lane & 7;
  const int tw = w * 32;

  const unsigned short* yb = ybf + (size_t)bz * T_ * R_;
  const float* nq = nsq + bz * T_;
  const unsigned short* Xb = xt + ((size_t)bz * D_ + d0) * T_;

// stage 128 d-rows x 64 j into Bs; 4 instrs/wave, linear LDS dest,
// pre-swizzled global source. (verified round 1)
#define STAGE(J0) do {                                                           \
    _Pragma("unroll")                                                            \
    for (int cc = 0; cc < 4; cc++) {                                             \
      const int rbase = w * 32 + cc * 8;                                         \
      const int row = rbase + srow;                                              \
      const int sw = (sslot ^ (row & 7)) * 8;                                    \
      __builtin_amdgcn_global_load_lds(                                          \
        (const __attribute__((address_space(1))) void*)(Xb + (size_t)row * T_ + (J0) + sw), \
        (__attribute__((address_space(3))) void*)(Bs + rbase * 64), 16, 0, 0);   \
    } } while (0)

  // hoisted t-side fragments
  short8 at[2]; float nnt[2]; f32x4 lsum4[2];
  #pragma unroll
  for (int tb = 0; tb < 2; tb++) {
    at[tb] = *(const short8*)(yb + (size_t)(t0 + tw + tb * 16 + m) * R_ + quad * 8);
    nnt[tb] = -nq[t0 + tw + tb * 16 + m];
    lsum4[tb] = (f32x4){0.f, 0.f, 0.f, 0.f};
  }

  f32x4 acc[4][4];
  #pragma unroll
  for (int i = 0; i < 4; i++)
    #pragma unroll
    for (int j = 0; j < 4; j++) acc[i][j] = (f32x4){0.f, 0.f, 0.f, 0.f};

  // prefetch j-tile 0 fragments
  short8 aj[4]; f32x4 njv[4];
  #pragma unroll
  for (int ja = 0; ja < 4; ja++) {
    aj[ja] = *(const short8*)(yb + (size_t)(ja * 16 + m) * R_ + quad * 8);
    njv[ja] = *(const f32x4*)(nq + ja * 16 + quad * 4);
  }

  for (int j0 = 0; j0 < T_; j0 += 64) {
    __syncthreads();   // prev PV done with As/Bs
    STAGE(j0);
    // rotate current fragments, prefetch next tile (overlaps scores+PV)
    short8 caj[4]; f32x4 cnj[4];
    #pragma unroll
    for (int ja = 0; ja < 4; ja++) { caj[ja] = aj[ja]; cnj[ja] = njv[ja]; }
    const int jn = (j0 + 64 < T_) ? j0 + 64 : 0;
    #pragma unroll
    for (int ja = 0; ja < 4; ja++) {
      aj[ja] = *(const short8*)(yb + (size_t)(jn + ja * 16 + m) * R_ + quad * 8);
      njv[ja] = *(const f32x4*)(nq + jn + ja * 16 + quad * 4);
    }
    // scores: c[r] = score(t = tw+tb*16+m, jloc = ja*16+quad*4+r); -nj-nt in C
    #pragma unroll
    for (int tb = 0; tb < 2; tb++) {
      const int trow = tw + tb * 16 + m;   // local t row 0..127; trow&7 == m&7
      #pragma unroll
      for (int ja = 0; ja < 4; ja++) {
        f32x4 cin;
        #pragma unroll
        for (int r = 0; r < 4; r++) cin[r] = nnt[tb] - cnj[ja][r];
        f32x4 c = __builtin_amdgcn_mfma_f32_16x16x32_bf16(caj[ja], at[tb], cin, 0, 0, 0);
        union { us4 c; unsigned u[2]; } pk;
        f32x4 p;
        #pragma unroll
        for (int r = 0; r < 4; r++) {
          p[r] = __builtin_amdgcn_exp2f(c[r]);
          lsum4[tb][r] += p[r];
        }
        pk.u[0] = pk2bf(p[0], p[1]);
        pk.u[1] = pk2bf(p[2], p[3]);
        // store src 16B-granule sb at physical granule sb^(trow&7), +8B if quad odd
        const int sb = ja * 2 + (quad >> 1);
        char* dst = (char*)As + trow * ASTR + ((sb ^ (trow & 7)) * 16) + (quad & 1) * 8;
        *(us4*)dst = pk.c;
      }
    }
    __syncthreads();   // As written + Bs arrived (compiler drains vmcnt)
    // PV: quadrant (wr, wc), m97-style reader on padded As + linear Bs
    #pragma unroll
    for (int ks = 0; ks < 2; ks++) {
      short8 af[4], bf[4];
      #pragma unroll
      for (int i = 0; i < 4; i++) {
        const int ra = wr + i * 16 + m;
        af[i] = *(const short8*)((const char*)As + ra * ASTR + (((ks * 4 + quad) ^ (m & 7)) * 16));
        const int cd = wc + i * 16 + m;
        bf[i] = *(const short8*)&Bs[cd * 64 + (((ks * 4 + quad) ^ (m & 7)) * 8)];
      }
      #pragma unroll
      for (int rb = 0; rb < 4; rb++)
        #pragma unroll
        for (int cb = 0; cb < 4; cb++)
          acc[rb][cb] = __builtin_amdgcn_mfma_f32_16x16x32_bf16(af[rb], bf[cb], acc[rb][cb], 0, 0, 0);
    }
  }
  // row sums: butterfly over quads, publish via tiny LDS
  #pragma unroll
  for (int tb = 0; tb < 2; tb++) {
    float lsum = lsum4[tb][0] + lsum4[tb][1] + lsum4[tb][2] + lsum4[tb][3];
    lsum += __shfl_xor(lsum, 16, 64);
    lsum += __shfl_xor(lsum, 32, 64);
    if (quad == 0) l_s[tw + tb * 16 + m] = lsum;
  }
  __syncthreads();
  // epilogue: out = acc / l   (C rows = quad*4+r, cols = m)
  #pragma unroll
  for (int rb = 0; rb < 4; rb++) {
    f32x4 lv = *(const f32x4*)&l_s[wr + rb * 16 + quad * 4];
    f32x4 inv;
    #pragma unroll
    for (int r = 0; r < 4; r++) inv[r] = 1.f / lv[r];
    float* ob = out + ((size_t)bz * T_ + t0 + wr + rb * 16 + quad * 4) * D_ + d0 + wc;
    #pragma unroll
    for (int cb = 0; cb < 4; cb++)
      #pragma unroll
      for (int r = 0; r < 4; r++)
        ob[(size_t)r * D_ + cb * 16 + m] = acc[rb][cb][r] * inv[r];
  }
#undef STAGE
}

extern "C" void kernel_launch(void* const* d_in, const int* in_sizes, int n_in,
                              void* d_out, int out_size, void* d_ws, size_t ws_size,
                              hipStream_t stream) {
  const float* x = (const float*)d_in[0];
  const float* U = (const float*)d_in[1];
  float* out = (float*)d_out;

  const size_t xt_b  = (size_t)B_ * D_ * T_ * 2;      // 16 MB
  const size_t ybf_b = (size_t)B_ * T_ * R_ * 2;      // 512 KB
  const size_t nsq_b = (size_t)B_ * T_ * 4;           // 32 KB
  const size_t yp_b  = (size_t)8 * B_ * R_ * T_ * 4;  // 8 MB partial y [slab][b][r][t]

  char* wp = (char*)d_ws;
  unsigned short* xtp = (unsigned short*)wp;                 wp += xt_b;
  unsigned short* ybf = (unsigned short*)wp;                 wp += ybf_b;
  float* nsq = (float*)wp;                                   wp += nsq_b;
  float* ypart = (float*)wp;                                 wp += yp_b;
  (void)ws_size; (void)in_sizes; (void)n_in; (void)out_size;

  hipLaunchKernelGGL(geo_prep, dim3(T_ / 128, B_, D_ / 128), dim3(256), 0, stream,
                     x, U, xtp, ypart);
  hipLaunchKernelGGL(geo_reduce, dim3(T_ / 32, B_), dim3(256), 0, stream,
                     ypart, ybf, nsq);
  hipLaunchKernelGGL(geo_fused, dim3((T_ / 128) * (D_ / 128), 1, B_), dim3(256), 0, stream,
                     ybf, nsq, xtp, out);
}